// Round 15
// baseline (19386.342 us; speedup 1.0000x reference)
//
#include <hip/hip_runtime.h>
#include <hip/hip_cooperative_groups.h>

#define B_ 64
#define H_ 1024
#define IN_ 512
#define S_ 256
#define L_ 6
#define NG_ 4096
#define NTASK 768            // 6 cells * 128 col-slices (8 H-cols x 4 gates)
#define NTICK (S_ + L_ - 1)

typedef __bf16 bf16x8 __attribute__((ext_vector_type(8)));
typedef float f32x4 __attribute__((ext_vector_type(4)));
typedef float f32x2 __attribute__((ext_vector_type(2)));
typedef unsigned short ushort8v __attribute__((ext_vector_type(8)));
typedef unsigned short ushort_t;

#define WP_BYTES 96468992ul
#define XB_BYTES 16777216ul
#define HBF_BYTES 1572864ul         // 2 slots * L * 65536 * 2B
#define LSLOT 65536ul               // packed h per layer (elems)
#define XSLOT 32768ul               // packed x per timestep (elems)

// W panel per (l,jb): unit (c*4 + nf*2 + ks) of 512 ushorts (1KB)
__host__ __device__ __forceinline__ size_t poff(int l, int jb) {
  return (l == 0) ? (size_t)jb * 49152ul
                  : 6291456ul + ((size_t)(l - 1) * 128 + jb) * 65536ul;
}

#define MFMA16(a, b, c) __builtin_amdgcn_mfma_f32_16x16x32_bf16(a, b, c, 0, 0, 0)
#define WAITN(n) asm volatile("s_waitcnt vmcnt(" #n ")" ::: "memory")
#define SB0() __builtin_amdgcn_sched_barrier(0)

__device__ __forceinline__ unsigned short f2bf(float f) {
  union { float f; unsigned u; } v; v.f = f;
  unsigned r = v.u + 0x7fffu + ((v.u >> 16) & 1u);
  return (unsigned short)(r >> 16);
}

// ---- XCD-tree grid barrier ----
// bar[xcd*32]: per-XCD arrive counters (8); bar[256]: root; bar[512+xcd*32]: gen mirrors.
// Arrive: <=96 RMWs per line in parallel across 8 lines (vs 768 on one line in
// grid.sync). Release: root master fans out to 8 mirrors; waiters poll "their" one.
__device__ __forceinline__ void tree_sync(int* __restrict__ bar, int gen, int nloc) {
  __syncthreads();
  if (threadIdx.x == 0) {
    __threadfence();                 // publish this WG's stores (L2 wb)
    const int xcd = blockIdx.x & 7;
    int a = __hip_atomic_fetch_add(&bar[xcd * 32], 1, __ATOMIC_ACQ_REL,
                                   __HIP_MEMORY_SCOPE_AGENT);
    if (a == nloc - 1) {
      __hip_atomic_store(&bar[xcd * 32], 0, __ATOMIC_RELAXED,
                         __HIP_MEMORY_SCOPE_AGENT);
      int r = __hip_atomic_fetch_add(&bar[256], 1, __ATOMIC_ACQ_REL,
                                     __HIP_MEMORY_SCOPE_AGENT);
      if (r == 7) {
        __hip_atomic_store(&bar[256], 0, __ATOMIC_RELAXED,
                           __HIP_MEMORY_SCOPE_AGENT);
#pragma unroll
        for (int i = 0; i < 8; ++i)
          __hip_atomic_store(&bar[512 + i * 32], gen, __ATOMIC_RELEASE,
                             __HIP_MEMORY_SCOPE_AGENT);
      }
    }
    while (__hip_atomic_load(&bar[512 + (blockIdx.x & 7) * 32], __ATOMIC_ACQUIRE,
                             __HIP_MEMORY_SCOPE_AGENT) < gen)
      __builtin_amdgcn_s_sleep(1);
  }
  __syncthreads();
}

// ---- one-time weight pack (proven layout) ----
__global__ void k_pack_w(const float* __restrict__ U0, const float* __restrict__ V0,
                         const float* __restrict__ U, const float* __restrict__ V,
                         ushort_t* __restrict__ Wp) {
  const int bx = blockIdx.x;              // 0..767
  const int l = bx >> 7, jb = bx & 127;
  ushort_t* __restrict__ panel = Wp + poff(l, jb);
  const int KU = (l == 0) ? IN_ : H_;
  const int NU = KU >> 6;
  const int NCH = NU + 16;
  const float* __restrict__ Usrc = (l == 0) ? U0 : U + (size_t)(l - 1) * H_ * NG_;
  const float* __restrict__ Vsrc = (l == 0) ? V0 : V + (size_t)(l - 1) * H_ * NG_;
  const int t = threadIdx.x, lane = t & 63, g4 = t >> 6;
  const int l15 = lane & 15, kg = lane >> 4;
  for (int p = 0; p < NCH; ++p) {
    const int gi = p * 4 + g4;
    const int c = gi >> 2, u = gi & 3, nf = u >> 1, ks = u & 1;
    const int n = (nf * 2 + (l15 >> 3)) * 1024 + jb * 8 + (l15 & 7);
    const int k = c * 64 + ks * 32 + kg * 8;
    const float* __restrict__ src =
        (c < NU) ? (Usrc + (size_t)k * NG_ + n)
                 : (Vsrc + (size_t)(k - KU) * NG_ + n);
    ushort8v uv;
#pragma unroll
    for (int e = 0; e < 8; ++e) uv[e] = f2bf(src[(size_t)e * NG_]);
    *(ushort8v*)(panel + (size_t)gi * 512 + lane * 8) = uv;
  }
}

// ---- one-time x -> bf16, packed-A unit order (c*8 + m*2 + ks) ----
__global__ void k_cvt_x(const float* __restrict__ x, ushort_t* __restrict__ xb) {
  const int tt = blockIdx.x;
  const int tid = threadIdx.x;
  const int b = tid >> 2, kq = (tid & 3) << 7;
  const float* __restrict__ src = x + ((size_t)b * S_ + tt) * IN_ + kq;
  ushort_t* __restrict__ dst = xb + (size_t)tt * XSLOT;
  const int m = b >> 4, l15 = b & 15;
#pragma unroll
  for (int kk = 0; kk < 128; kk += 8) {
    float4 v0 = *(const float4*)(src + kk);
    float4 v1 = *(const float4*)(src + kk + 4);
    ushort8v u = { f2bf(v0.x), f2bf(v0.y), f2bf(v0.z), f2bf(v0.w),
                   f2bf(v1.x), f2bf(v1.y), f2bf(v1.z), f2bf(v1.w) };
    const int k = kq + kk;
    const int c = k >> 6, ksl = (k >> 5) & 1, kg = (k & 31) >> 3;
    *(ushort8v*)(dst + (((size_t)c * 8 + m * 2 + ksl) * 64 + kg * 16 + l15) * 8) = u;
  }
}

// Per-wave K-quarter GEMM: ALL 64 rows x 32 N-cols over Q=NCH/4 chunks.
template<int NCH>
__device__ __forceinline__ void gemm_q(f32x4 acc[4][2],
                                       const ushort_t* __restrict__ panel,
                                       const ushort_t* __restrict__ A1,
                                       const ushort_t* __restrict__ A2,
                                       int w, int lane) {
  constexpr int NU = NCH - 16;
  constexpr int Q = NCH / 4;
  bf16x8 Wb[2][4];
  bf16x8 Ab[2][8];
#define LDU(p) (*(const bf16x8*)(p))
#define ISSUE(c, bk) do { \
    const ushort_t* wp_ = panel + (size_t)(c) * 2048 + lane * 8; \
    Wb[bk][0] = LDU(wp_); \
    Wb[bk][1] = LDU(wp_ + 512); \
    Wb[bk][2] = LDU(wp_ + 1024); \
    Wb[bk][3] = LDU(wp_ + 1536); \
    const ushort_t* ap_ = ((c) < NU \
        ? A1 + (size_t)(c) * 4096 : A2 + (size_t)((c) - NU) * 4096) + lane * 8; \
    Ab[bk][0] = LDU(ap_); \
    Ab[bk][1] = LDU(ap_ + 512); \
    Ab[bk][2] = LDU(ap_ + 1024); \
    Ab[bk][3] = LDU(ap_ + 1536); \
    Ab[bk][4] = LDU(ap_ + 2048); \
    Ab[bk][5] = LDU(ap_ + 2560); \
    Ab[bk][6] = LDU(ap_ + 3072); \
    Ab[bk][7] = LDU(ap_ + 3584); \
  } while (0)
  const int c0 = w * Q;
  ISSUE(c0, 0);
  if (Q > 1) ISSUE(c0 + 1, 1);
  SB0();
#pragma unroll
  for (int j = 0; j < Q; ++j) {
    if (j + 1 < Q) { WAITN(12); } else { WAITN(0); }
    SB0();
    const int bk = j & 1;
#pragma unroll
    for (int ks = 0; ks < 2; ++ks)
#pragma unroll
      for (int m = 0; m < 4; ++m) {
        acc[m][0] = MFMA16(Ab[bk][m * 2 + ks], Wb[bk][ks], acc[m][0]);
        acc[m][1] = MFMA16(Ab[bk][m * 2 + ks], Wb[bk][2 + ks], acc[m][1]);
      }
    SB0();
    if (j + 2 < Q) ISSUE(c0 + j + 2, bk);
    SB0();
  }
#undef ISSUE
#undef LDU
}

__global__ void __launch_bounds__(256, 3)
k_lstm(const ushort_t* __restrict__ xb,
       const ushort_t* __restrict__ Wp,
       const float* __restrict__ b0,
       const float* __restrict__ bL,
       ushort_t* __restrict__ hbf,   // [2][L][LSLOT] packed bf16, pre-zeroed
       int* __restrict__ bar,        // tree-barrier state, pre-zeroed
       float* __restrict__ out, int multi) {
  float* __restrict__ seq = out;                           // [B][S][H]
  float* __restrict__ hf = out + (size_t)B_ * S_ * H_;     // [L][B][H]
  float* __restrict__ cf = hf + (size_t)L_ * B_ * H_;      // [L][B][H]
  __shared__ float zsp[4][64][33];   // per-wave K-partials (padded)
  __shared__ float hstF[512];        // h staging: [row][8 cols]

  const int tid = threadIdx.x;
  const int w = tid >> 6;        // wave = K-quarter
  const int lane = tid & 63;
  const int l15 = lane & 15;
  const int kg = lane >> 4;
  const int wg = blockIdx.x;
  const int nwg = gridDim.x;
  const int nloc = nwg >> 3;     // WGs per XCD class (nwg multiple of 8)

  // gate-phase identity: thread owns (row, 2 H-cols), fixed per task
  const int grow = tid >> 2;
  const int gq = (tid & 3) << 1;    // hcl0: 0,2,4,6
  float creg[2] = {0.f, 0.f};

  for (int T = 0; T < NTICK; ++T) {
    for (int task = wg; task < NTASK; task += nwg) {
      const int l = task >> 7;
      const int jb = task & 127;
      const int t = T - l;
      if (t < 0 || t >= S_) continue;
      const ushort_t* __restrict__ hprev = hbf + (size_t)((T + 1) & 1) * (L_ * LSLOT);
      ushort_t* __restrict__ hcur = hbf + (size_t)(T & 1) * (L_ * LSLOT) + (size_t)l * LSLOT;
      const ushort_t* __restrict__ panel = Wp + poff(l, jb);
      const ushort_t* __restrict__ A2 = hprev + (size_t)l * LSLOT;

      f32x4 acc[4][2];
#pragma unroll
      for (int m = 0; m < 4; ++m) {
        acc[m][0] = (f32x4){0.f, 0.f, 0.f, 0.f};
        acc[m][1] = (f32x4){0.f, 0.f, 0.f, 0.f};
      }
      if (l == 0)
        gemm_q<24>(acc, panel, xb + (size_t)t * XSLOT, A2, w, lane);
      else
        gemm_q<32>(acc, panel, hprev + (size_t)(l - 1) * LSLOT, A2, w, lane);

      // write partials: row = m*16 + kg*4 + j, col32 = nf*16 + l15
#pragma unroll
      for (int m = 0; m < 4; ++m)
#pragma unroll
        for (int nf = 0; nf < 2; ++nf)
#pragma unroll
          for (int j = 0; j < 4; ++j)
            zsp[w][m * 16 + kg * 4 + j][nf * 16 + l15] = acc[m][nf][j];
      __syncthreads();

      // ---- gate phase: thread = (row, 2 cols); sum 4 K-partials ----
      {
        const int hc0 = (jb << 3) + gq;
        const float* __restrict__ bias = (l == 0) ? b0 : (bL + (size_t)(l - 1) * NG_);
        const size_t cbase = ((size_t)l * B_ + grow) * H_ + hc0;
        f32x2 cold;
        if (multi) {
          if (t > 0) cold = *(const f32x2*)(cf + cbase);
          else cold = (f32x2){0.f, 0.f};
        } else {
          cold = (f32x2){creg[0], creg[1]};
        }
        f32x2 hv2, cn2;
#pragma unroll
        for (int q = 0; q < 2; ++q) {
          const int hcl = gq + q;
          float z[4];
#pragma unroll
          for (int g = 0; g < 4; ++g) {
            const int c32 = (g >> 1) * 16 + (g & 1) * 8 + hcl;
            z[g] = zsp[0][grow][c32] + zsp[1][grow][c32] +
                   zsp[2][grow][c32] + zsp[3][grow][c32] +
                   bias[g * 1024 + hc0 + q];
          }
          float iv = 1.f / (1.f + expf(-z[0]));
          float fv = 1.f / (1.f + expf(-z[1]));
          float gv = tanhf(z[2]);
          float ov = 1.f / (1.f + expf(-z[3]));
          float cn = fv * cold[q] + iv * gv;
          cn2[q] = cn;
          creg[q] = cn;
          float hv = ov * tanhf(cn);
          hv2[q] = hv;
          hstF[grow * 8 + hcl] = hv;
        }
        if (multi || t == S_ - 1) *(f32x2*)(cf + cbase) = cn2;
        if (t == S_ - 1) *(f32x2*)(hf + cbase) = hv2;
        if (l == L_ - 1)
          *(f32x2*)(seq + ((size_t)grow * S_ + t) * H_ + hc0) = hv2;
      }
      __syncthreads();

      // ---- h write in packed-A unit order (unit = c*8 + m*2 + ks) ----
      if (tid < 64) {
        const int m = tid >> 4, lr = tid & 15;
        const float* hp = &hstF[(m * 16 + lr) * 8];
        ushort8v u8 = { f2bf(hp[0]), f2bf(hp[1]), f2bf(hp[2]), f2bf(hp[3]),
                        f2bf(hp[4]), f2bf(hp[5]), f2bf(hp[6]), f2bf(hp[7]) };
        *(ushort8v*)(hcur +
                     (((size_t)(jb >> 3) * 8 + m * 2 + ((jb >> 2) & 1)) * 64 +
                      ((jb & 3) * 16 + lr)) * 8) = u8;
      }
      __syncthreads();               // zsp/hstF safe before next task
    }
    tree_sync(bar, T + 1, nloc);
  }
}

extern "C" void kernel_launch(void* const* d_in, const int* in_sizes, int n_in,
                              void* d_out, int out_size, void* d_ws, size_t ws_size,
                              hipStream_t stream) {
  const float* x = (const float*)d_in[0];
  const float* U0 = (const float*)d_in[1];
  const float* V0 = (const float*)d_in[2];
  const float* b0 = (const float*)d_in[3];
  const float* U = (const float*)d_in[4];
  const float* V = (const float*)d_in[5];
  const float* bL = (const float*)d_in[6];
  float* out = (float*)d_out;

  char* ws = (char*)d_ws;
  unsigned short* Wp = (unsigned short*)ws;
  unsigned short* xb = (unsigned short*)(ws + WP_BYTES);
  unsigned short* hbf = (unsigned short*)(ws + WP_BYTES + XB_BYTES);
  int* bar = (int*)(ws + WP_BYTES + XB_BYTES + HBF_BYTES);

  hipLaunchKernelGGL(k_pack_w, dim3(NTASK), dim3(256), 0, stream, U0, V0, U, V, Wp);
  hipLaunchKernelGGL(k_cvt_x, dim3(S_), dim3(256), 0, stream, x, xb);
  hipMemsetAsync(hbf, 0, HBF_BYTES, stream);
  hipMemsetAsync(bar, 0, 4096, stream);

  int maxB = 0;
  hipOccupancyMaxActiveBlocksPerMultiprocessor(&maxB, k_lstm, 256, 0);
  int nwg = maxB * 256;
  if (nwg > NTASK) nwg = NTASK;
  if (nwg < 64) nwg = 64;
  int multi = (nwg < NTASK) ? 1 : 0;

  void* args[] = { (void*)&xb, (void*)&Wp, (void*)&b0, (void*)&bL,
                   (void*)&hbf, (void*)&bar, (void*)&out, (void*)&multi };
  hipError_t e = hipLaunchCooperativeKernel((void*)k_lstm, dim3(nwg), dim3(256),
                                            args, 0, stream);
  if (e != hipSuccess) {
    (void)hipGetLastError();
    nwg = 256; multi = 1;
    void* args2[] = { (void*)&xb, (void*)&Wp, (void*)&b0, (void*)&bL,
                      (void*)&hbf, (void*)&bar, (void*)&out, (void*)&multi };
    hipLaunchCooperativeKernel((void*)k_lstm, dim3(nwg), dim3(256),
                               args2, 0, stream);
  }
}

// Round 16
// 15092.397 us; speedup vs baseline: 1.2845x; 1.2845x over previous
//
#include <hip/hip_runtime.h>
#include <hip/hip_cooperative_groups.h>

#define B_ 64
#define H_ 1024
#define IN_ 512
#define S_ 256
#define L_ 6
#define NG_ 4096
#define NTASK 768            // 6 cells * 128 col-slices (8 H-cols x 4 gates)
#define NTICK (S_ + L_ - 1)

typedef __bf16 bf16x8 __attribute__((ext_vector_type(8)));
typedef float f32x4 __attribute__((ext_vector_type(4)));
typedef float f32x2 __attribute__((ext_vector_type(2)));
typedef unsigned short ushort8v __attribute__((ext_vector_type(8)));
typedef unsigned short ushort_t;

#define WP_BYTES 96468992ul
#define XB_BYTES 16777216ul
#define HBF_ELEMS 786432ul          // 2 slots * L * 65536
#define LSLOT 65536ul               // packed h per layer (elems)
#define XSLOT 32768ul               // packed x per timestep (elems)

// W panel per (l,jb): unit (c*4 + nf*2 + ks) of 512 ushorts (1KB)
__host__ __device__ __forceinline__ size_t poff(int l, int jb) {
  return (l == 0) ? (size_t)jb * 49152ul
                  : 6291456ul + ((size_t)(l - 1) * 128 + jb) * 65536ul;
}

#define MFMA16(a, b, c) __builtin_amdgcn_mfma_f32_16x16x32_bf16(a, b, c, 0, 0, 0)
#define WAITN(n) asm volatile("s_waitcnt vmcnt(" #n ")" ::: "memory")
#define SB0() __builtin_amdgcn_sched_barrier(0)

__device__ __forceinline__ unsigned short f2bf(float f) {
  union { float f; unsigned u; } v; v.f = f;
  unsigned r = v.u + 0x7fffu + ((v.u >> 16) & 1u);
  return (unsigned short)(r >> 16);
}

// ---- one-time weight pack (proven layout) ----
__global__ void k_pack_w(const float* __restrict__ U0, const float* __restrict__ V0,
                         const float* __restrict__ U, const float* __restrict__ V,
                         ushort_t* __restrict__ Wp) {
  const int bx = blockIdx.x;              // 0..767
  const int l = bx >> 7, jb = bx & 127;
  ushort_t* __restrict__ panel = Wp + poff(l, jb);
  const int KU = (l == 0) ? IN_ : H_;
  const int NU = KU >> 6;
  const int NCH = NU + 16;
  const float* __restrict__ Usrc = (l == 0) ? U0 : U + (size_t)(l - 1) * H_ * NG_;
  const float* __restrict__ Vsrc = (l == 0) ? V0 : V + (size_t)(l - 1) * H_ * NG_;
  const int t = threadIdx.x, lane = t & 63, g4 = t >> 6;
  const int l15 = lane & 15, kg = lane >> 4;
  for (int p = 0; p < NCH; ++p) {
    const int gi = p * 4 + g4;
    const int c = gi >> 2, u = gi & 3, nf = u >> 1, ks = u & 1;
    const int n = (nf * 2 + (l15 >> 3)) * 1024 + jb * 8 + (l15 & 7);
    const int k = c * 64 + ks * 32 + kg * 8;
    const float* __restrict__ src =
        (c < NU) ? (Usrc + (size_t)k * NG_ + n)
                 : (Vsrc + (size_t)(k - KU) * NG_ + n);
    ushort8v uv;
#pragma unroll
    for (int e = 0; e < 8; ++e) uv[e] = f2bf(src[(size_t)e * NG_]);
    *(ushort8v*)(panel + (size_t)gi * 512 + lane * 8) = uv;
  }
}

// ---- one-time x -> bf16, packed-A unit order (c*8 + m*2 + ks) ----
__global__ void k_cvt_x(const float* __restrict__ x, ushort_t* __restrict__ xb) {
  const int tt = blockIdx.x;
  const int tid = threadIdx.x;
  const int b = tid >> 2, kq = (tid & 3) << 7;
  const float* __restrict__ src = x + ((size_t)b * S_ + tt) * IN_ + kq;
  ushort_t* __restrict__ dst = xb + (size_t)tt * XSLOT;
  const int m = b >> 4, l15 = b & 15;
#pragma unroll
  for (int kk = 0; kk < 128; kk += 8) {
    float4 v0 = *(const float4*)(src + kk);
    float4 v1 = *(const float4*)(src + kk + 4);
    ushort8v u = { f2bf(v0.x), f2bf(v0.y), f2bf(v0.z), f2bf(v0.w),
                   f2bf(v1.x), f2bf(v1.y), f2bf(v1.z), f2bf(v1.w) };
    const int k = kq + kk;
    const int c = k >> 6, ksl = (k >> 5) & 1, kg = (k & 31) >> 3;
    *(ushort8v*)(dst + (((size_t)c * 8 + m * 2 + ksl) * 64 + kg * 16 + l15) * 8) = u;
  }
}

// Per-wave K-quarter GEMM: ALL 64 rows x 32 N-cols over Q=NCH/4 chunks.
// acc[m][nf]; depth-2 bank pipeline (12 loads/chunk).
template<int NCH>
__device__ __forceinline__ void gemm_q(f32x4 acc[4][2],
                                       const ushort_t* __restrict__ panel,
                                       const ushort_t* __restrict__ A1,
                                       const ushort_t* __restrict__ A2,
                                       int w, int lane) {
  constexpr int NU = NCH - 16;
  constexpr int Q = NCH / 4;
  bf16x8 Wb[2][4];
  bf16x8 Ab[2][8];
#define LDU(p) (*(const bf16x8*)(p))
#define ISSUE(c, bk) do { \
    const ushort_t* wp_ = panel + (size_t)(c) * 2048 + lane * 8; \
    Wb[bk][0] = LDU(wp_); \
    Wb[bk][1] = LDU(wp_ + 512); \
    Wb[bk][2] = LDU(wp_ + 1024); \
    Wb[bk][3] = LDU(wp_ + 1536); \
    const ushort_t* ap_ = ((c) < NU \
        ? A1 + (size_t)(c) * 4096 : A2 + (size_t)((c) - NU) * 4096) + lane * 8; \
    Ab[bk][0] = LDU(ap_); \
    Ab[bk][1] = LDU(ap_ + 512); \
    Ab[bk][2] = LDU(ap_ + 1024); \
    Ab[bk][3] = LDU(ap_ + 1536); \
    Ab[bk][4] = LDU(ap_ + 2048); \
    Ab[bk][5] = LDU(ap_ + 2560); \
    Ab[bk][6] = LDU(ap_ + 3072); \
    Ab[bk][7] = LDU(ap_ + 3584); \
  } while (0)
  const int c0 = w * Q;
  ISSUE(c0, 0);
  if (Q > 1) ISSUE(c0 + 1, 1);
  SB0();
#pragma unroll
  for (int j = 0; j < Q; ++j) {
    if (j + 1 < Q) { WAITN(12); } else { WAITN(0); }
    SB0();
    const int bk = j & 1;
#pragma unroll
    for (int ks = 0; ks < 2; ++ks)
#pragma unroll
      for (int m = 0; m < 4; ++m) {
        acc[m][0] = MFMA16(Ab[bk][m * 2 + ks], Wb[bk][ks], acc[m][0]);
        acc[m][1] = MFMA16(Ab[bk][m * 2 + ks], Wb[bk][2 + ks], acc[m][1]);
      }
    SB0();
    if (j + 2 < Q) ISSUE(c0 + j + 2, bk);
    SB0();
  }
#undef ISSUE
#undef LDU
}

__global__ void __launch_bounds__(256, 3)
k_lstm(const ushort_t* __restrict__ xb,
       const ushort_t* __restrict__ Wp,
       const float* __restrict__ b0,
       const float* __restrict__ bL,
       ushort_t* __restrict__ hbf,   // [2][L][LSLOT] packed bf16, pre-zeroed
       float* __restrict__ out, int multi) {
  cooperative_groups::grid_group grid = cooperative_groups::this_grid();
  float* __restrict__ seq = out;                           // [B][S][H]
  float* __restrict__ hf = out + (size_t)B_ * S_ * H_;     // [L][B][H]
  float* __restrict__ cf = hf + (size_t)L_ * B_ * H_;      // [L][B][H]
  __shared__ float zsp[4][64][33];   // per-wave K-partials (padded)
  __shared__ float hstF[512];        // h staging: [row][8 cols]

  const int tid = threadIdx.x;
  const int w = tid >> 6;        // wave = K-quarter
  const int lane = tid & 63;
  const int l15 = lane & 15;
  const int kg = lane >> 4;
  const int wg = blockIdx.x;
  const int nwg = gridDim.x;

  // gate-phase identity: thread owns (row, 2 H-cols), fixed per task
  const int grow = tid >> 2;
  const int gq = (tid & 3) << 1;    // hcl0: 0,2,4,6
  float creg[2] = {0.f, 0.f};

  for (int T = 0; T < NTICK; ++T) {
    for (int task = wg; task < NTASK; task += nwg) {
      const int l = task >> 7;
      const int jb = task & 127;
      const int t = T - l;
      if (t < 0 || t >= S_) continue;
      const ushort_t* __restrict__ hprev = hbf + (size_t)((T + 1) & 1) * (L_ * LSLOT);
      ushort_t* __restrict__ hcur = hbf + (size_t)(T & 1) * (L_ * LSLOT) + (size_t)l * LSLOT;
      const ushort_t* __restrict__ panel = Wp + poff(l, jb);
      const ushort_t* __restrict__ A2 = hprev + (size_t)l * LSLOT;

      f32x4 acc[4][2];
#pragma unroll
      for (int m = 0; m < 4; ++m) {
        acc[m][0] = (f32x4){0.f, 0.f, 0.f, 0.f};
        acc[m][1] = (f32x4){0.f, 0.f, 0.f, 0.f};
      }
      if (l == 0)
        gemm_q<24>(acc, panel, xb + (size_t)t * XSLOT, A2, w, lane);
      else
        gemm_q<32>(acc, panel, hprev + (size_t)(l - 1) * LSLOT, A2, w, lane);

      // write partials: row = m*16 + kg*4 + j, col32 = nf*16 + l15
#pragma unroll
      for (int m = 0; m < 4; ++m)
#pragma unroll
        for (int nf = 0; nf < 2; ++nf)
#pragma unroll
          for (int j = 0; j < 4; ++j)
            zsp[w][m * 16 + kg * 4 + j][nf * 16 + l15] = acc[m][nf][j];
      __syncthreads();

      // ---- gate phase: thread = (row, 2 cols); sum 4 K-partials ----
      {
        const int hc0 = (jb << 3) + gq;
        const float* __restrict__ bias = (l == 0) ? b0 : (bL + (size_t)(l - 1) * NG_);
        const size_t cbase = ((size_t)l * B_ + grow) * H_ + hc0;
        f32x2 cold;
        if (multi) {
          if (t > 0) cold = *(const f32x2*)(cf + cbase);
          else cold = (f32x2){0.f, 0.f};
        } else {
          cold = (f32x2){creg[0], creg[1]};
        }
        f32x2 hv2, cn2;
#pragma unroll
        for (int q = 0; q < 2; ++q) {
          const int hcl = gq + q;
          float z[4];
#pragma unroll
          for (int g = 0; g < 4; ++g) {
            const int c32 = (g >> 1) * 16 + (g & 1) * 8 + hcl;
            z[g] = zsp[0][grow][c32] + zsp[1][grow][c32] +
                   zsp[2][grow][c32] + zsp[3][grow][c32] +
                   bias[g * 1024 + hc0 + q];
          }
          float iv = 1.f / (1.f + expf(-z[0]));
          float fv = 1.f / (1.f + expf(-z[1]));
          float gv = tanhf(z[2]);
          float ov = 1.f / (1.f + expf(-z[3]));
          float cn = fv * cold[q] + iv * gv;
          cn2[q] = cn;
          creg[q] = cn;
          float hv = ov * tanhf(cn);
          hv2[q] = hv;
          hstF[grow * 8 + hcl] = hv;
        }
        if (multi || t == S_ - 1) *(f32x2*)(cf + cbase) = cn2;
        if (t == S_ - 1) *(f32x2*)(hf + cbase) = hv2;
        if (l == L_ - 1)
          *(f32x2*)(seq + ((size_t)grow * S_ + t) * H_ + hc0) = hv2;
      }
      __syncthreads();

      // ---- h write in packed-A unit order (unit = c*8 + m*2 + ks) ----
      if (tid < 64) {
        const int m = tid >> 4, lr = tid & 15;
        const float* hp = &hstF[(m * 16 + lr) * 8];
        ushort8v u8 = { f2bf(hp[0]), f2bf(hp[1]), f2bf(hp[2]), f2bf(hp[3]),
                        f2bf(hp[4]), f2bf(hp[5]), f2bf(hp[6]), f2bf(hp[7]) };
        *(ushort8v*)(hcur +
                     (((size_t)(jb >> 3) * 8 + m * 2 + ((jb >> 2) & 1)) * 64 +
                      ((jb & 3) * 16 + lr)) * 8) = u8;
      }
      __syncthreads();               // zsp/hstF safe before next task
    }
    grid.sync();
  }
}

extern "C" void kernel_launch(void* const* d_in, const int* in_sizes, int n_in,
                              void* d_out, int out_size, void* d_ws, size_t ws_size,
                              hipStream_t stream) {
  const float* x = (const float*)d_in[0];
  const float* U0 = (const float*)d_in[1];
  const float* V0 = (const float*)d_in[2];
  const float* b0 = (const float*)d_in[3];
  const float* U = (const float*)d_in[4];
  const float* V = (const float*)d_in[5];
  const float* bL = (const float*)d_in[6];
  float* out = (float*)d_out;

  char* ws = (char*)d_ws;
  unsigned short* Wp = (unsigned short*)ws;
  unsigned short* xb = (unsigned short*)(ws + WP_BYTES);
  unsigned short* hbf = (unsigned short*)(ws + WP_BYTES + XB_BYTES);

  hipLaunchKernelGGL(k_pack_w, dim3(NTASK), dim3(256), 0, stream, U0, V0, U, V, Wp);
  hipLaunchKernelGGL(k_cvt_x, dim3(S_), dim3(256), 0, stream, x, xb);
  hipMemsetAsync(hbf, 0, HBF_ELEMS * 2, stream);

  int maxB = 0;
  hipOccupancyMaxActiveBlocksPerMultiprocessor(&maxB, k_lstm, 256, 0);
  int nwg = maxB * 256;
  if (nwg > NTASK) nwg = NTASK;
  if (nwg < 64) nwg = 64;
  int multi = (nwg < NTASK) ? 1 : 0;

  void* args[] = { (void*)&xb, (void*)&Wp, (void*)&b0, (void*)&bL,
                   (void*)&hbf, (void*)&out, (void*)&multi };
  hipError_t e = hipLaunchCooperativeKernel((void*)k_lstm, dim3(nwg), dim3(256),
                                            args, 0, stream);
  if (e != hipSuccess) {
    (void)hipGetLastError();
    nwg = 256; multi = 1;
    void* args2[] = { (void*)&xb, (void*)&Wp, (void*)&b0, (void*)&bL,
                      (void*)&hbf, (void*)&out, (void*)&multi };
    hipLaunchCooperativeKernel((void*)k_lstm, dim3(nwg), dim3(256),
                               args2, 0, stream);
  }
}